// Round 1
// baseline (590.556 us; speedup 1.0000x reference)
//
#include <hip/hip_runtime.h>

// LSTM: B=4096 sequences, T=2048 steps, H=15 hidden units, scalar in/out per step.
// Decomposition: 16 lanes per batch element; lane l owns hidden unit l
// (computes gates i,f,g,o for unit l -> cell update is lane-local).
// h broadcast within the 16-lane group via LDS (1 write + 4x b128 broadcast reads).
// 65536 threads = 1024 waves = 1 wave/SIMD across all 256 CUs.

#define HID 15
#define T_LEN 2048
#define B_TOT 4096

__device__ __forceinline__ float fast_sig(float x) {
    // 1 / (1 + 2^(-x*log2e))  -> v_mul, v_exp_f32, v_add, v_rcp_f32
    return __builtin_amdgcn_rcpf(1.0f + __builtin_amdgcn_exp2f(x * -1.44269504088896341f));
}
__device__ __forceinline__ float fast_tanh(float x) {
    // 2*sigmoid(2x) - 1
    return fmaf(2.0f, __builtin_amdgcn_rcpf(1.0f + __builtin_amdgcn_exp2f(x * -2.88539008177792681f)), -1.0f);
}

__global__ __launch_bounds__(256, 1) void lstm_seq_kernel(
    const float* __restrict__ x,      // (B, T)
    const float* __restrict__ W_ih,   // (60, 1)
    const float* __restrict__ W_hh,   // (60, 15)
    const float* __restrict__ b_ih,   // (60,)
    const float* __restrict__ b_hh,   // (60,)
    const float* __restrict__ W_lin,  // (1, 15)
    const float* __restrict__ b_lin,  // (1,)
    float* __restrict__ out)          // (B, T)
{
    __shared__ __align__(16) float lds_h[16][16];   // [group in block][unit]

    const int tid  = threadIdx.x;
    const int grp  = tid >> 4;          // 0..15 group within block
    const int lane = tid & 15;          // unit index (lane 15 duplicates unit 14)
    const int b    = blockIdx.x * 16 + grp;
    const int u    = (lane < HID) ? lane : (HID - 1);

    // --- load per-lane weights into registers ---
    float wih[4], bias[4], whh[4][HID];
#pragma unroll
    for (int r = 0; r < 4; ++r) {
        const int row = r * HID + u;    // rows: i=u, f=15+u, g=30+u, o=45+u
        wih[r]  = W_ih[row];
        bias[r] = b_ih[row] + b_hh[row];
#pragma unroll
        for (int k = 0; k < HID; ++k) whh[r][k] = W_hh[row * HID + k];
    }
    float wlin[HID];
#pragma unroll
    for (int k = 0; k < HID; ++k) wlin[k] = W_lin[k];
    const float blin = b_lin[0];

    float c = 0.0f;
    float hk[16];
#pragma unroll
    for (int k = 0; k < 16; ++k) hk[k] = 0.0f;

    const float4* __restrict__ x4 = (const float4*)(x + (size_t)b * T_LEN);
    float4* __restrict__ o4       = (float4*)(out + (size_t)b * T_LEN);

    for (int t0 = 0; t0 < T_LEN / 4; ++t0) {
        const float4 xv = x4[t0];
        float ov[4];
#pragma unroll
        for (int s = 0; s < 4; ++s) {
            const float xt = (s == 0) ? xv.x : (s == 1) ? xv.y : (s == 2) ? xv.z : xv.w;

            // gates for this lane's unit: i, f, g, o
            float gi = fmaf(xt, wih[0], bias[0]);
            float gf = fmaf(xt, wih[1], bias[1]);
            float gg = fmaf(xt, wih[2], bias[2]);
            float go = fmaf(xt, wih[3], bias[3]);
#pragma unroll
            for (int k = 0; k < HID; ++k) {
                gi = fmaf(hk[k], whh[0][k], gi);
                gf = fmaf(hk[k], whh[1][k], gf);
                gg = fmaf(hk[k], whh[2][k], gg);
                go = fmaf(hk[k], whh[3][k], go);
            }

            // cell update (fully lane-local)
            c = fast_sig(gf) * c + fast_sig(gi) * fast_tanh(gg);
            const float hl = fast_sig(go) * fast_tanh(c);

            // broadcast h within the 16-lane group via LDS
            lds_h[grp][lane] = hl;      // same-wave producer/consumer, DS pipe in-order
            const float4 h0 = *(const float4*)&lds_h[grp][0];
            const float4 h1 = *(const float4*)&lds_h[grp][4];
            const float4 h2 = *(const float4*)&lds_h[grp][8];
            const float4 h3 = *(const float4*)&lds_h[grp][12];
            hk[0]  = h0.x; hk[1]  = h0.y; hk[2]  = h0.z; hk[3]  = h0.w;
            hk[4]  = h1.x; hk[5]  = h1.y; hk[6]  = h1.z; hk[7]  = h1.w;
            hk[8]  = h2.x; hk[9]  = h2.y; hk[10] = h2.z; hk[11] = h2.w;
            hk[12] = h3.x; hk[13] = h3.y; hk[14] = h3.z; hk[15] = h3.w;

            // output projection (all lanes compute; lane 0 writes)
            float o = blin;
#pragma unroll
            for (int k = 0; k < HID; ++k) o = fmaf(hk[k], wlin[k], o);
            ov[s] = o;
        }
        if (lane == 0) {
            o4[t0] = make_float4(ov[0], ov[1], ov[2], ov[3]);
        }
    }
}

extern "C" void kernel_launch(void* const* d_in, const int* in_sizes, int n_in,
                              void* d_out, int out_size, void* d_ws, size_t ws_size,
                              hipStream_t stream) {
    const float* x     = (const float*)d_in[0];
    const float* W_ih  = (const float*)d_in[1];
    const float* W_hh  = (const float*)d_in[2];
    const float* b_ih  = (const float*)d_in[3];
    const float* b_hh  = (const float*)d_in[4];
    const float* W_lin = (const float*)d_in[5];
    const float* b_lin = (const float*)d_in[6];
    float* out = (float*)d_out;

    dim3 grid(B_TOT / 16);   // 256 blocks
    dim3 block(256);         // 16 groups of 16 lanes
    lstm_seq_kernel<<<grid, block, 0, stream>>>(x, W_ih, W_hh, b_ih, b_hh,
                                                W_lin, b_lin, out);
}